// Round 20
// baseline (299.345 us; speedup 1.0000x reference)
//
#include <hip/hip_runtime.h>
#include <hip/hip_bf16.h>
#include <hip/hip_fp16.h>
#include <math.h>

#define N_NODES 50000
#define N_EDGES 800000
#define IN_DIM 128
#define NHEAD 4
#define NREL 64
#define HC 256              // NHEAD * 64 (both layers: H*HID = H*OUT = 256)
#define NEG_SLOPE 0.2f
#define SCAN_B ((N_NODES + 255) / 256)   // 196 blocks
#define XB (N_NODES / 16)                // 3125 prep_x blocks
#define HB ((N_EDGES + 255) / 256)       // 3125 hist/fill blocks

using short8 = __attribute__((ext_vector_type(8))) short;   // 8 bf16 (4 VGPRs)
using f32x4  = __attribute__((ext_vector_type(4))) float;

// async global->LDS, 16B per lane (zero VGPR staging)
__device__ __forceinline__ void load_lds16s(const short* g, short* l) {
  __builtin_amdgcn_global_load_lds(
      (const __attribute__((address_space(1))) unsigned int*)g,
      (__attribute__((address_space(3))) unsigned int*)l, 16, 0, 0);
}

__device__ __forceinline__ unsigned bf16rne(float v) {
  unsigned u = __float_as_uint(v);
  return (u + 0x7FFFu + ((u >> 16) & 1u)) >> 16;
}

// ============ hist + rank: ONE atomic pass for the whole CSR build ===========
__global__ __launch_bounds__(256) void hist_rank_kernel(
    const int* __restrict__ dst, int* __restrict__ deg,
    unsigned short* __restrict__ rank) {
  int e = blockIdx.x * blockDim.x + threadIdx.x;
  if (e < N_EDGES) {
    int r = atomicAdd(&deg[dst[e]], 1);
    rank[e] = (unsigned short)r;
  }
}

// ============ fused prep: prep_x(l1) | relalpha(x2) | prep_w(x2) ============
__global__ __launch_bounds__(256) void fused_prep(
    const float* __restrict__ x, short* __restrict__ xfh, short* __restrict__ xfl,
    const float* __restrict__ rel1, const float* __restrict__ We1, const float* __restrict__ ae1,
    const float* __restrict__ rel2, const float* __restrict__ We2, const float* __restrict__ ae2,
    float* __restrict__ tab1, float* __restrict__ tab2,
    const float* __restrict__ W1, short* __restrict__ w1h, short* __restrict__ w1l,
    const float* __restrict__ W2, short* __restrict__ w2h, short* __restrict__ w2l) {
  const int bid = blockIdx.x;
  const int t = threadIdx.x;
  __shared__ float plds[16 * 132];

  if (bid < XB) {
    const int K = IN_DIM, LW = K + 4;
    for (int i = t * 4; i < 16 * K; i += 1024) {
      int r = i / K, k = i - r * K;
      *(float4*)&plds[r * LW + k] = *(const float4*)&x[(size_t)(bid * 16 + r) * K + k];
    }
    __syncthreads();
    for (int c = t; c < 2 * K; c += 256) {
      int p_k = c >> 6, l = c & 63;
      int r = l & 15, k0 = p_k * 32 + (l >> 4) * 8;
      unsigned hp[4], lp[4];
#pragma unroll
      for (int q = 0; q < 4; ++q) {
        float v0 = plds[r * LW + k0 + q * 2];
        float v1 = plds[r * LW + k0 + q * 2 + 1];
        unsigned h0 = bf16rne(v0), h1 = bf16rne(v1);
        float l0 = (v0 - __uint_as_float(h0 << 16)) * 256.0f;
        float l1 = (v1 - __uint_as_float(h1 << 16)) * 256.0f;
        hp[q] = h0 | (h1 << 16);
        lp[q] = bf16rne(l0) | (bf16rne(l1) << 16);
      }
      size_t base = ((size_t)(bid * (K >> 5) + p_k) * 64 + l) * 8;
      *(int4*)&xfh[base] = make_int4(hp[0], hp[1], hp[2], hp[3]);
      *(int4*)&xfl[base] = make_int4(lp[0], lp[1], lp[2], lp[3]);
    }
    return;
  }
  if (bid < XB + 128) {
    const int rb = bid - XB;
    const int layer = rb >> 6, r = rb & 63;
    const float* rel = layer ? rel2 : rel1;
    const float* We  = layer ? We2  : We1;
    const float* ae  = layer ? ae2  : ae1;
    float* tab       = layer ? tab2 : tab1;
    const int K      = layer ? 64   : IN_DIM;
    float acc = 0.f;
    for (int k = 0; k < K; ++k) acc += rel[(size_t)r * K + k] * We[(size_t)k * HC + t];
    int h = t >> 6, lane = t & 63;
    float p = acc * ae[t];
#pragma unroll
    for (int off = 32; off > 0; off >>= 1) p += __shfl_down(p, off);
    if (lane == 0) tab[r * NHEAD + h] = p;
    return;
  }
  {
    const int wb = bid - (XB + 128);
    const float* W; short* Wh; short* Wl; int K, c;
    if (wb < 16) { W = W1; Wh = w1h; Wl = w1l; K = IN_DIM; c = wb * 256 + t; }
    else         { W = W2; Wh = w2h; Wl = w2l; K = 64;     c = (wb - 16) * 256 + t; }
    const int KP = K >> 5;
    if (c >= 16 * KP * 64) return;
    const int p = c >> 6, l = c & 63;
    const int p_c = p / KP, p_k = p - p_c * KP;
    const int col = p_c * 16 + (l & 15), k0 = p_k * 32 + (l >> 4) * 8;
    unsigned hp[4], lp[4];
#pragma unroll
    for (int q = 0; q < 4; ++q) {
      float v0 = W[(size_t)(k0 + q * 2) * HC + col];
      float v1 = W[(size_t)(k0 + q * 2 + 1) * HC + col];
      unsigned h0 = bf16rne(v0), h1 = bf16rne(v1);
      float l0 = (v0 - __uint_as_float(h0 << 16)) * 256.0f;
      float l1 = (v1 - __uint_as_float(h1 << 16)) * 256.0f;
      hp[q] = h0 | (h1 << 16);
      lp[q] = bf16rne(l0) | (bf16rne(l1) << 16);
    }
    size_t base = (size_t)c * 8;
    *(int4*)&Wh[base] = make_int4(hp[0], hp[1], hp[2], hp[3]);
    *(int4*)&Wl[base] = make_int4(lp[0], lp[1], lp[2], lp[3]);
  }
}

// ============ MFMA GEMM + fused alpha: 64 rows x 128 cols per block ==========
__global__ __launch_bounds__(256, 4) void gemm_mfma(
    const short* __restrict__ Xh, const short* __restrict__ Xl,
    const short* __restrict__ Wh, const short* __restrict__ Wl,
    const float* __restrict__ a_s, const float* __restrict__ a_d,
    __half2* __restrict__ xs16, float* __restrict__ asrc, float* __restrict__ adst,
    int M, int K) {
  __shared__ short lds[2][24 * 512];     // 24KB per buf: [Xh4|Xl4|Wh8|Wl8]
  const int t = threadIdx.x;
  const int wv = t >> 6, l = t & 63;
  const int KP = K >> 5;
  const int pr0 = blockIdx.x * 4;
  const int pc0 = blockIdx.y * 8;
  const int c0 = blockIdx.y * 128;

#define STAGE(BI, PK)                                                         \
  {                                                                           \
    _Pragma("unroll")                                                         \
    for (int j = 0; j < 6; ++j) {                                             \
      const int s = wv * 6 + j;                                               \
      const short* srcp;                                                      \
      if (s < 4)       srcp = Xh + (((size_t)(pr0 + s) * KP + (PK)) << 9);    \
      else if (s < 8)  srcp = Xl + (((size_t)(pr0 + s - 4) * KP + (PK)) << 9);\
      else if (s < 16) srcp = Wh + (((size_t)(pc0 + s - 8) * KP + (PK)) << 9);\
      else             srcp = Wl + (((size_t)(pc0 + s - 16) * KP + (PK)) << 9);\
      load_lds16s(srcp + l * 8, &lds[BI][s * 512]);                           \
    }                                                                         \
  }

  f32x4 acc0[8], acc1[8];
#pragma unroll
  for (int i = 0; i < 8; ++i)
#pragma unroll
    for (int c = 0; c < 4; ++c) { acc0[i][c] = 0.f; acc1[i][c] = 0.f; }

  STAGE(0, 0);
  for (int pk = 0; pk < KP; ++pk) {
    const int cur = pk & 1;
    if (pk + 1 < KP) {
      STAGE(cur ^ 1, pk + 1);
      asm volatile("s_waitcnt vmcnt(6)" ::: "memory");
    } else {
      asm volatile("s_waitcnt vmcnt(0)" ::: "memory");
    }
    __builtin_amdgcn_s_barrier();
    __builtin_amdgcn_sched_barrier(0);
    const short8 ah = *(const short8*)&lds[cur][(0 + wv) * 512 + l * 8];
    const short8 al = *(const short8*)&lds[cur][(4 + wv) * 512 + l * 8];
#pragma unroll
    for (int t8 = 0; t8 < 8; ++t8) {
      const short8 bh = *(const short8*)&lds[cur][(8 + t8) * 512 + l * 8];
      const short8 bl = *(const short8*)&lds[cur][(16 + t8) * 512 + l * 8];
      acc0[t8] = __builtin_amdgcn_mfma_f32_16x16x32_bf16(ah, bh, acc0[t8], 0, 0, 0);
      acc1[t8] = __builtin_amdgcn_mfma_f32_16x16x32_bf16(ah, bl, acc1[t8], 0, 0, 0);
      acc1[t8] = __builtin_amdgcn_mfma_f32_16x16x32_bf16(al, bh, acc1[t8], 0, 0, 0);
    }
    asm volatile("" ::: "memory");
    __builtin_amdgcn_s_barrier();
  }
#undef STAGE

  const int col_l = l & 15;
  const int row_l = (l >> 4) * 4;
  __half* xsh = (__half*)xs16;
  float asv[8], adv[8];
#pragma unroll
  for (int t8 = 0; t8 < 8; ++t8) {
    asv[t8] = a_s[c0 + t8 * 16 + col_l];
    adv[t8] = a_d[c0 + t8 * 16 + col_l];
  }
  float sp[2][4], dp[2][4];
#pragma unroll
  for (int hl = 0; hl < 2; ++hl)
#pragma unroll
    for (int r = 0; r < 4; ++r) { sp[hl][r] = 0.f; dp[hl][r] = 0.f; }

#pragma unroll
  for (int t8 = 0; t8 < 8; ++t8) {
    const int hl = t8 >> 2;
#pragma unroll
    for (int r = 0; r < 4; ++r) {
      const float v = acc0[t8][r] + acc1[t8][r] * (1.0f / 256.0f);
      const int row = (pr0 + wv) * 16 + row_l + r;
      if (row < M) {
        const int col = c0 + t8 * 16 + col_l;
        xsh[(size_t)row * HC + col] = __float2half(v);
      }
      sp[hl][r] += v * asv[t8];
      dp[hl][r] += v * adv[t8];
    }
  }
#pragma unroll
  for (int off = 1; off < 16; off <<= 1) {
#pragma unroll
    for (int hl = 0; hl < 2; ++hl)
#pragma unroll
      for (int r = 0; r < 4; ++r) {
        sp[hl][r] += __shfl_xor(sp[hl][r], off);
        dp[hl][r] += __shfl_xor(dp[hl][r], off);
      }
  }
  if (col_l == 0) {
#pragma unroll
    for (int hl = 0; hl < 2; ++hl) {
      const int head = blockIdx.y * 2 + hl;
#pragma unroll
      for (int r = 0; r < 4; ++r) {
        const int row = (pr0 + wv) * 16 + row_l + r;
        if (row < M) {
          asrc[row * NHEAD + head] = sp[hl][r];
          adst[row * NHEAD + head] = dp[hl][r];
        }
      }
    }
  }
}

// ============ CSR scan chain ============
__global__ __launch_bounds__(256) void block_sum_kernel(
    const int* __restrict__ deg, int* __restrict__ bsum) {
  int i = blockIdx.x * 256 + threadIdx.x;
  int v = (i < N_NODES) ? deg[i] : 0;
#pragma unroll
  for (int off = 32; off > 0; off >>= 1) v += __shfl_down(v, off);
  __shared__ int w[4];
  if ((threadIdx.x & 63) == 0) w[threadIdx.x >> 6] = v;
  __syncthreads();
  if (threadIdx.x == 0) bsum[blockIdx.x] = w[0] + w[1] + w[2] + w[3];
}

__global__ __launch_bounds__(256) void scan_bsum_kernel(
    const int* __restrict__ bsum, int* __restrict__ boff) {
  __shared__ int s[256];
  int t = threadIdx.x;
  int v = (t < SCAN_B) ? bsum[t] : 0;
  s[t] = v;
  __syncthreads();
  for (int off = 1; off < 256; off <<= 1) {
    int u = (t >= off) ? s[t - off] : 0;
    __syncthreads();
    s[t] += u;
    __syncthreads();
  }
  boff[t] = (t == 0) ? 0 : s[t - 1];
}

__global__ __launch_bounds__(256) void scan_final_kernel(
    const int* __restrict__ deg, const int* __restrict__ boff,
    int* __restrict__ rowptr) {
  __shared__ int s[256];
  int t = threadIdx.x;
  int i = blockIdx.x * 256 + t;
  int v = (i < N_NODES) ? deg[i] : 0;
  s[t] = v;
  __syncthreads();
  for (int off = 1; off < 256; off <<= 1) {
    int u = (t >= off) ? s[t - off] : 0;
    __syncthreads();
    s[t] += u;
    __syncthreads();
  }
  int excl = boff[blockIdx.x] + s[t] - v;
  if (i < N_NODES) rowptr[i] = excl;
  if (t == 0 && blockIdx.x == 0) rowptr[N_NODES] = N_EDGES;
}

// atomic-free CSR fill
__global__ __launch_bounds__(256) void fill_kernel(
    const int* __restrict__ src, const int* __restrict__ dst,
    const int* __restrict__ etype, const unsigned short* __restrict__ rank,
    const int* __restrict__ rowptr, int* __restrict__ csrp) {
  int e = blockIdx.x * blockDim.x + threadIdx.x;
  if (e >= N_EDGES) return;
  int d = dst[e];
  int pos = rowptr[d] + rank[e];
  csrp[pos] = src[e] | (etype[e] << 16);
}

// ============ gat_node v2: lane-specialized two-phase, ONE WAVE PER NODE =====
// Per 16-edge chunk: phase A = lane j computes logit/exp for (edge j>>2,
// head j&3) — no SIMT redundancy (was 16x replicated). phase B = broadcast
// w via ds_bpermute, s via readlane; payload MAC via v_fma_mix_f32 (fp16
// operand direct, no cvts). tab in LDS. den reduced once at the end.
__global__ __launch_bounds__(256) void gat_node_kernel(
    const int* __restrict__ rowptr, const int* __restrict__ csr,
    const float* __restrict__ asrc, const float* __restrict__ adst,
    const float* __restrict__ tab, const __half2* __restrict__ xs16,
    const float* __restrict__ b, float* __restrict__ out,
    short* __restrict__ oxh, short* __restrict__ oxl, int mode) {
  __shared__ float lds_tab[NREL * NHEAD];   // 1KB
  const int t = threadIdx.x;
  lds_tab[t] = tab[t];
  __syncthreads();
  const int n = (blockIdx.x * blockDim.x + t) >> 6;
  if (n >= N_NODES) return;
  const int lane = t & 63;
  const int hlog = lane & 3;              // phase-A head
  const int eoff = lane >> 2;             // phase-A edge slot (0..15)
  const int hpay = lane >> 4;             // phase-B head (cols lane*4..+3)
  const unsigned voff = (unsigned)lane * 2;   // half2 offset within row
  const int i0 = rowptr[n], i1 = rowptr[n + 1];
  const float adn = adst[n * NHEAD + hlog];

  float4 acc = make_float4(0.f, 0.f, 0.f, 0.f);
  float denp = 0.f;

  for (int base = i0; base < i1; base += 16) {
    const int nE = min(16, i1 - base);
    // ---- phase A: one logit per lane ----
    float w = 0.f;
    int sreg = 0;
    if (eoff < nE) {
      const int p = csr[base + eoff];
      const int s = p & 0xFFFF;
      sreg = s;
      const int r = p >> 16;
      float l = asrc[s * NHEAD + hlog] + adn + lds_tab[r * NHEAD + hlog];
      l = fmaxf(l, NEG_SLOPE * l);        // leaky (slope<1)
      w = __expf(l);
    }
    denp += w;
    // ---- phase B: gather + fma_mix accumulate ----
#pragma unroll
    for (int k = 0; k < 16; ++k) {
      if (k < nE) {                        // uniform per wave
        const int s_k = __shfl(sreg, k * 4);            // readlane (uniform)
        const float w_k = __shfl(w, k * 4 + hpay);      // ds_bpermute
        const uint2 q = *(const uint2*)&xs16[((unsigned)s_k << 7) + voff];
        asm volatile(
            "v_fma_mix_f32 %0, %2, %3, %0 op_sel_hi:[0,1,0]\n\t"
            "v_fma_mix_f32 %1, %2, %3, %1 op_sel:[0,1,0] op_sel_hi:[0,1,0]"
            : "+v"(acc.x), "+v"(acc.y) : "v"(w_k), "v"(q.x));
        asm volatile(
            "v_fma_mix_f32 %0, %2, %3, %0 op_sel_hi:[0,1,0]\n\t"
            "v_fma_mix_f32 %1, %2, %3, %1 op_sel:[0,1,0] op_sel_hi:[0,1,0]"
            : "+v"(acc.z), "+v"(acc.w) : "v"(w_k), "v"(q.y));
      }
    }
  }

  // den per head: sum lanes ≡ hlog (mod 4)
#pragma unroll
  for (int off = 4; off < 64; off <<= 1) denp += __shfl_xor(denp, off);
  const float den = __shfl(denp, hpay);   // lane hpay holds head-hpay sum
  const float rd = (den > 0.f) ? (0.25f / den) : 0.f;
  float4 y = make_float4(acc.x * rd, acc.y * rd, acc.z * rd, acc.w * rd);
#pragma unroll
  for (int off = 16; off < 64; off <<= 1) {
    y.x += __shfl_xor(y.x, off);
    y.y += __shfl_xor(y.y, off);
    y.z += __shfl_xor(y.z, off);
    y.w += __shfl_xor(y.w, off);
  }
  if (lane < 16) {
    const float4 bb = *(const float4*)&b[lane * 4];
    y.x += bb.x; y.y += bb.y; y.z += bb.z; y.w += bb.w;
    if (mode) {
      // relu + split-bf16, panel-order store (verified mapping, K=64)
      y.x = fmaxf(y.x, 0.f); y.y = fmaxf(y.y, 0.f);
      y.z = fmaxf(y.z, 0.f); y.w = fmaxf(y.w, 0.f);
      unsigned h0 = bf16rne(y.x), h1 = bf16rne(y.y);
      unsigned h2 = bf16rne(y.z), h3 = bf16rne(y.w);
      float l0 = (y.x - __uint_as_float(h0 << 16)) * 256.0f;
      float l1 = (y.y - __uint_as_float(h1 << 16)) * 256.0f;
      float l2 = (y.z - __uint_as_float(h2 << 16)) * 256.0f;
      float l3 = (y.w - __uint_as_float(h3 << 16)) * 256.0f;
      unsigned hp0 = h0 | (h1 << 16), hp1 = h2 | (h3 << 16);
      unsigned lp0 = bf16rne(l0) | (bf16rne(l1) << 16);
      unsigned lp1 = bf16rne(l2) | (bf16rne(l3) << 16);
      const int pk = lane >> 3;
      const int lip = (n & 15) + ((lane >> 1) & 3) * 16;
      const int j0 = (lane & 1) * 4;
      size_t base = ((size_t)((n >> 4) * 2 + pk) * 64 + lip) * 8 + j0;
      *(uint2*)&oxh[base] = make_uint2(hp0, hp1);
      *(uint2*)&oxl[base] = make_uint2(lp0, lp1);
    } else {
      *(float4*)&out[(size_t)n * 64 + lane * 4] = y;
    }
  }
}

extern "C" void kernel_launch(void* const* d_in, const int* in_sizes, int n_in,
                              void* d_out, int out_size, void* d_ws, size_t ws_size,
                              hipStream_t stream) {
  const float* x   = (const float*)d_in[0];
  const int* eidx  = (const int*)d_in[1];
  const int* etype = (const int*)d_in[2];
  const float* rel1 = (const float*)d_in[3];
  const float* W1   = (const float*)d_in[4];
  const float* We1  = (const float*)d_in[5];
  const float* as1  = (const float*)d_in[6];
  const float* ad1  = (const float*)d_in[7];
  const float* ae1  = (const float*)d_in[8];
  const float* b1   = (const float*)d_in[9];
  const float* rel2 = (const float*)d_in[10];
  const float* W2   = (const float*)d_in[11];
  const float* We2  = (const float*)d_in[12];
  const float* as2  = (const float*)d_in[13];
  const float* ad2  = (const float*)d_in[14];
  const float* ae2  = (const float*)d_in[15];
  const float* b2   = (const float*)d_in[16];
  const int* src = eidx;
  const int* dst = eidx + N_EDGES;

  // ---- workspace layout (256B-aligned regions) ----
  char* wsb = (char*)d_ws;
  size_t off = 0;
  auto carve = [&](size_t bytes) { char* p = wsb + off; off = (off + bytes + 255) & ~(size_t)255; return p; };
  __half2* xs16 = (__half2*)carve((size_t)N_NODES * HC * 2);          // 25.6MB
  float* asrc = (float*)carve((size_t)N_NODES * NHEAD * 4);
  float* adst = (float*)carve((size_t)N_NODES * NHEAD * 4);
  float* tab1 = (float*)carve(NREL * NHEAD * 4);
  float* tab2 = (float*)carve(NREL * NHEAD * 4);
  short* xfh  = (short*)carve(((size_t)N_NODES * IN_DIM + 32768) * 2);// 12.9MB
  short* xfl  = (short*)carve(((size_t)N_NODES * IN_DIM + 32768) * 2);
  short* w1h  = (short*)carve(256 * IN_DIM * 2);
  short* w1l  = (short*)carve(256 * IN_DIM * 2);
  short* w2h  = (short*)carve(256 * 64 * 2);
  short* w2l  = (short*)carve(256 * 64 * 2);
  int* deg    = (int*)carve(N_NODES * 4);
  int* rowptr = (int*)carve((N_NODES + 1) * 4);
  unsigned short* rank = (unsigned short*)carve((size_t)N_EDGES * 2);
  int* csrp   = (int*)carve((size_t)N_EDGES * 4);
  int* bsum   = (int*)carve(256 * 4);
  int* boff   = (int*)carve(256 * 4);

  hipMemsetAsync(deg, 0, N_NODES * sizeof(int), stream);

  // one atomic pass: counts + per-edge ranks
  hist_rank_kernel<<<HB, 256, 0, stream>>>(dst, deg, rank);

  // fused prep: prep_x(l1) | relalpha x2 | prep_w x2
  fused_prep<<<XB + 128 + 16 + 8, 256, 0, stream>>>(
      x, xfh, xfl,
      rel1, We1, ae1, rel2, We2, ae2, tab1, tab2,
      W1, w1h, w1l, W2, w2h, w2l);

  block_sum_kernel<<<SCAN_B, 256, 0, stream>>>(deg, bsum);
  scan_bsum_kernel<<<1, 256, 0, stream>>>(bsum, boff);
  scan_final_kernel<<<SCAN_B, 256, 0, stream>>>(deg, boff, rowptr);
  fill_kernel<<<HB, 256, 0, stream>>>(src, dst, etype, rank, rowptr, csrp);

  const dim3 gemm_grid((N_NODES + 63) / 64, 2);
  const int GB = (N_NODES * 64 + 255) / 256;   // one wave per node

  // ================= layer 1 =================
  gemm_mfma<<<gemm_grid, 256, 0, stream>>>(xfh, xfl, w1h, w1l, as1, ad1, xs16, asrc, adst, N_NODES, IN_DIM);
  gat_node_kernel<<<GB, 256, 0, stream>>>(rowptr, csrp, asrc, adst, tab1, xs16,
                                          b1, nullptr, xfh, xfl, 1);

  // ================= layer 2 =================
  gemm_mfma<<<gemm_grid, 256, 0, stream>>>(xfh, xfl, w2h, w2l, as2, ad2, xs16, asrc, adst, N_NODES, 64);
  gat_node_kernel<<<GB, 256, 0, stream>>>(rowptr, csrp, asrc, adst, tab2, xs16,
                                          b2, (float*)d_out, nullptr, nullptr, 0);
}

// Round 21
// 272.180 us; speedup vs baseline: 1.0998x; 1.0998x over previous
//
#include <hip/hip_runtime.h>
#include <hip/hip_bf16.h>
#include <hip/hip_fp16.h>
#include <math.h>

#define N_NODES 50000
#define N_EDGES 800000
#define IN_DIM 128
#define NHEAD 4
#define NREL 64
#define HC 256              // NHEAD * 64 (both layers: H*HID = H*OUT = 256)
#define NEG_SLOPE 0.2f
#define SCAN_B ((N_NODES + 255) / 256)   // 196 blocks
#define XB (N_NODES / 16)                // 3125 prep_x blocks
#define HB ((N_EDGES + 255) / 256)       // 3125 hist/fill blocks

using short8 = __attribute__((ext_vector_type(8))) short;   // 8 bf16 (4 VGPRs)
using f32x4  = __attribute__((ext_vector_type(4))) float;

// async global->LDS, 16B per lane (zero VGPR staging)
__device__ __forceinline__ void load_lds16s(const short* g, short* l) {
  __builtin_amdgcn_global_load_lds(
      (const __attribute__((address_space(1))) unsigned int*)g,
      (__attribute__((address_space(3))) unsigned int*)l, 16, 0, 0);
}

__device__ __forceinline__ unsigned bf16rne(float v) {
  unsigned u = __float_as_uint(v);
  return (u + 0x7FFFu + ((u >> 16) & 1u)) >> 16;
}

// ============ hist + rank: ONE atomic pass for the whole CSR build ===========
__global__ __launch_bounds__(256) void hist_rank_kernel(
    const int* __restrict__ dst, int* __restrict__ deg,
    unsigned short* __restrict__ rank) {
  int e = blockIdx.x * blockDim.x + threadIdx.x;
  if (e < N_EDGES) {
    int r = atomicAdd(&deg[dst[e]], 1);
    rank[e] = (unsigned short)r;
  }
}

// ============ fused prep: prep_x(l1) | relalpha(x2) | prep_w(x2) ============
__global__ __launch_bounds__(256) void fused_prep(
    const float* __restrict__ x, short* __restrict__ xfh, short* __restrict__ xfl,
    const float* __restrict__ rel1, const float* __restrict__ We1, const float* __restrict__ ae1,
    const float* __restrict__ rel2, const float* __restrict__ We2, const float* __restrict__ ae2,
    float* __restrict__ tab1, float* __restrict__ tab2,
    const float* __restrict__ W1, short* __restrict__ w1h, short* __restrict__ w1l,
    const float* __restrict__ W2, short* __restrict__ w2h, short* __restrict__ w2l) {
  const int bid = blockIdx.x;
  const int t = threadIdx.x;
  __shared__ float plds[16 * 132];

  if (bid < XB) {
    const int K = IN_DIM, LW = K + 4;
    for (int i = t * 4; i < 16 * K; i += 1024) {
      int r = i / K, k = i - r * K;
      *(float4*)&plds[r * LW + k] = *(const float4*)&x[(size_t)(bid * 16 + r) * K + k];
    }
    __syncthreads();
    for (int c = t; c < 2 * K; c += 256) {
      int p_k = c >> 6, l = c & 63;
      int r = l & 15, k0 = p_k * 32 + (l >> 4) * 8;
      unsigned hp[4], lp[4];
#pragma unroll
      for (int q = 0; q < 4; ++q) {
        float v0 = plds[r * LW + k0 + q * 2];
        float v1 = plds[r * LW + k0 + q * 2 + 1];
        unsigned h0 = bf16rne(v0), h1 = bf16rne(v1);
        float l0 = (v0 - __uint_as_float(h0 << 16)) * 256.0f;
        float l1 = (v1 - __uint_as_float(h1 << 16)) * 256.0f;
        hp[q] = h0 | (h1 << 16);
        lp[q] = bf16rne(l0) | (bf16rne(l1) << 16);
      }
      size_t base = ((size_t)(bid * (K >> 5) + p_k) * 64 + l) * 8;
      *(int4*)&xfh[base] = make_int4(hp[0], hp[1], hp[2], hp[3]);
      *(int4*)&xfl[base] = make_int4(lp[0], lp[1], lp[2], lp[3]);
    }
    return;
  }
  if (bid < XB + 128) {
    const int rb = bid - XB;
    const int layer = rb >> 6, r = rb & 63;
    const float* rel = layer ? rel2 : rel1;
    const float* We  = layer ? We2  : We1;
    const float* ae  = layer ? ae2  : ae1;
    float* tab       = layer ? tab2 : tab1;
    const int K      = layer ? 64   : IN_DIM;
    float acc = 0.f;
    for (int k = 0; k < K; ++k) acc += rel[(size_t)r * K + k] * We[(size_t)k * HC + t];
    int h = t >> 6, lane = t & 63;
    float p = acc * ae[t];
#pragma unroll
    for (int off = 32; off > 0; off >>= 1) p += __shfl_down(p, off);
    if (lane == 0) tab[r * NHEAD + h] = p;
    return;
  }
  {
    const int wb = bid - (XB + 128);
    const float* W; short* Wh; short* Wl; int K, c;
    if (wb < 16) { W = W1; Wh = w1h; Wl = w1l; K = IN_DIM; c = wb * 256 + t; }
    else         { W = W2; Wh = w2h; Wl = w2l; K = 64;     c = (wb - 16) * 256 + t; }
    const int KP = K >> 5;
    if (c >= 16 * KP * 64) return;
    const int p = c >> 6, l = c & 63;
    const int p_c = p / KP, p_k = p - p_c * KP;
    const int col = p_c * 16 + (l & 15), k0 = p_k * 32 + (l >> 4) * 8;
    unsigned hp[4], lp[4];
#pragma unroll
    for (int q = 0; q < 4; ++q) {
      float v0 = W[(size_t)(k0 + q * 2) * HC + col];
      float v1 = W[(size_t)(k0 + q * 2 + 1) * HC + col];
      unsigned h0 = bf16rne(v0), h1 = bf16rne(v1);
      float l0 = (v0 - __uint_as_float(h0 << 16)) * 256.0f;
      float l1 = (v1 - __uint_as_float(h1 << 16)) * 256.0f;
      hp[q] = h0 | (h1 << 16);
      lp[q] = bf16rne(l0) | (bf16rne(l1) << 16);
    }
    size_t base = (size_t)c * 8;
    *(int4*)&Wh[base] = make_int4(hp[0], hp[1], hp[2], hp[3]);
    *(int4*)&Wl[base] = make_int4(lp[0], lp[1], lp[2], lp[3]);
  }
}

// ============ MFMA GEMM + fused alpha: 64 rows x 128 cols per block ==========
__global__ __launch_bounds__(256, 4) void gemm_mfma(
    const short* __restrict__ Xh, const short* __restrict__ Xl,
    const short* __restrict__ Wh, const short* __restrict__ Wl,
    const float* __restrict__ a_s, const float* __restrict__ a_d,
    __half2* __restrict__ xs16, float* __restrict__ asrc, float* __restrict__ adst,
    int M, int K) {
  __shared__ short lds[2][24 * 512];     // 24KB per buf: [Xh4|Xl4|Wh8|Wl8]
  const int t = threadIdx.x;
  const int wv = t >> 6, l = t & 63;
  const int KP = K >> 5;
  const int pr0 = blockIdx.x * 4;
  const int pc0 = blockIdx.y * 8;
  const int c0 = blockIdx.y * 128;

#define STAGE(BI, PK)                                                         \
  {                                                                           \
    _Pragma("unroll")                                                         \
    for (int j = 0; j < 6; ++j) {                                             \
      const int s = wv * 6 + j;                                               \
      const short* srcp;                                                      \
      if (s < 4)       srcp = Xh + (((size_t)(pr0 + s) * KP + (PK)) << 9);    \
      else if (s < 8)  srcp = Xl + (((size_t)(pr0 + s - 4) * KP + (PK)) << 9);\
      else if (s < 16) srcp = Wh + (((size_t)(pc0 + s - 8) * KP + (PK)) << 9);\
      else             srcp = Wl + (((size_t)(pc0 + s - 16) * KP + (PK)) << 9);\
      load_lds16s(srcp + l * 8, &lds[BI][s * 512]);                           \
    }                                                                         \
  }

  f32x4 acc0[8], acc1[8];
#pragma unroll
  for (int i = 0; i < 8; ++i)
#pragma unroll
    for (int c = 0; c < 4; ++c) { acc0[i][c] = 0.f; acc1[i][c] = 0.f; }

  STAGE(0, 0);
  for (int pk = 0; pk < KP; ++pk) {
    const int cur = pk & 1;
    if (pk + 1 < KP) {
      STAGE(cur ^ 1, pk + 1);
      asm volatile("s_waitcnt vmcnt(6)" ::: "memory");
    } else {
      asm volatile("s_waitcnt vmcnt(0)" ::: "memory");
    }
    __builtin_amdgcn_s_barrier();
    __builtin_amdgcn_sched_barrier(0);
    const short8 ah = *(const short8*)&lds[cur][(0 + wv) * 512 + l * 8];
    const short8 al = *(const short8*)&lds[cur][(4 + wv) * 512 + l * 8];
#pragma unroll
    for (int t8 = 0; t8 < 8; ++t8) {
      const short8 bh = *(const short8*)&lds[cur][(8 + t8) * 512 + l * 8];
      const short8 bl = *(const short8*)&lds[cur][(16 + t8) * 512 + l * 8];
      acc0[t8] = __builtin_amdgcn_mfma_f32_16x16x32_bf16(ah, bh, acc0[t8], 0, 0, 0);
      acc1[t8] = __builtin_amdgcn_mfma_f32_16x16x32_bf16(ah, bl, acc1[t8], 0, 0, 0);
      acc1[t8] = __builtin_amdgcn_mfma_f32_16x16x32_bf16(al, bh, acc1[t8], 0, 0, 0);
    }
    asm volatile("" ::: "memory");
    __builtin_amdgcn_s_barrier();
  }
#undef STAGE

  const int col_l = l & 15;
  const int row_l = (l >> 4) * 4;
  __half* xsh = (__half*)xs16;
  float asv[8], adv[8];
#pragma unroll
  for (int t8 = 0; t8 < 8; ++t8) {
    asv[t8] = a_s[c0 + t8 * 16 + col_l];
    adv[t8] = a_d[c0 + t8 * 16 + col_l];
  }
  float sp[2][4], dp[2][4];
#pragma unroll
  for (int hl = 0; hl < 2; ++hl)
#pragma unroll
    for (int r = 0; r < 4; ++r) { sp[hl][r] = 0.f; dp[hl][r] = 0.f; }

#pragma unroll
  for (int t8 = 0; t8 < 8; ++t8) {
    const int hl = t8 >> 2;
#pragma unroll
    for (int r = 0; r < 4; ++r) {
      const float v = acc0[t8][r] + acc1[t8][r] * (1.0f / 256.0f);
      const int row = (pr0 + wv) * 16 + row_l + r;
      if (row < M) {
        const int col = c0 + t8 * 16 + col_l;
        xsh[(size_t)row * HC + col] = __float2half(v);
      }
      sp[hl][r] += v * asv[t8];
      dp[hl][r] += v * adv[t8];
    }
  }
#pragma unroll
  for (int off = 1; off < 16; off <<= 1) {
#pragma unroll
    for (int hl = 0; hl < 2; ++hl)
#pragma unroll
      for (int r = 0; r < 4; ++r) {
        sp[hl][r] += __shfl_xor(sp[hl][r], off);
        dp[hl][r] += __shfl_xor(dp[hl][r], off);
      }
  }
  if (col_l == 0) {
#pragma unroll
    for (int hl = 0; hl < 2; ++hl) {
      const int head = blockIdx.y * 2 + hl;
#pragma unroll
      for (int r = 0; r < 4; ++r) {
        const int row = (pr0 + wv) * 16 + row_l + r;
        if (row < M) {
          asrc[row * NHEAD + head] = sp[hl][r];
          adst[row * NHEAD + head] = dp[hl][r];
        }
      }
    }
  }
}

// ============ CSR scan chain ============
__global__ __launch_bounds__(256) void block_sum_kernel(
    const int* __restrict__ deg, int* __restrict__ bsum) {
  int i = blockIdx.x * 256 + threadIdx.x;
  int v = (i < N_NODES) ? deg[i] : 0;
#pragma unroll
  for (int off = 32; off > 0; off >>= 1) v += __shfl_down(v, off);
  __shared__ int w[4];
  if ((threadIdx.x & 63) == 0) w[threadIdx.x >> 6] = v;
  __syncthreads();
  if (threadIdx.x == 0) bsum[blockIdx.x] = w[0] + w[1] + w[2] + w[3];
}

__global__ __launch_bounds__(256) void scan_bsum_kernel(
    const int* __restrict__ bsum, int* __restrict__ boff) {
  __shared__ int s[256];
  int t = threadIdx.x;
  int v = (t < SCAN_B) ? bsum[t] : 0;
  s[t] = v;
  __syncthreads();
  for (int off = 1; off < 256; off <<= 1) {
    int u = (t >= off) ? s[t - off] : 0;
    __syncthreads();
    s[t] += u;
    __syncthreads();
  }
  boff[t] = (t == 0) ? 0 : s[t - 1];
}

__global__ __launch_bounds__(256) void scan_final_kernel(
    const int* __restrict__ deg, const int* __restrict__ boff,
    int* __restrict__ rowptr) {
  __shared__ int s[256];
  int t = threadIdx.x;
  int i = blockIdx.x * 256 + t;
  int v = (i < N_NODES) ? deg[i] : 0;
  s[t] = v;
  __syncthreads();
  for (int off = 1; off < 256; off <<= 1) {
    int u = (t >= off) ? s[t - off] : 0;
    __syncthreads();
    s[t] += u;
    __syncthreads();
  }
  int excl = boff[blockIdx.x] + s[t] - v;
  if (i < N_NODES) rowptr[i] = excl;
  if (t == 0 && blockIdx.x == 0) rowptr[N_NODES] = N_EDGES;
}

// atomic-free CSR fill
__global__ __launch_bounds__(256) void fill_kernel(
    const int* __restrict__ src, const int* __restrict__ dst,
    const int* __restrict__ etype, const unsigned short* __restrict__ rank,
    const int* __restrict__ rowptr, int* __restrict__ csrp) {
  int e = blockIdx.x * blockDim.x + threadIdx.x;
  if (e >= N_EDGES) return;
  int d = dst[e];
  int pos = rowptr[d] + rank[e];
  csrp[pos] = src[e] | (etype[e] << 16);
}

// ============ gat_node (R19 structure, unroll-8): ONE WAVE PER NODE ==========
// All 64 lanes compute logits redundantly per head-group (R20 proved the
// lane-specialized variant regresses: gather pipeline matters more than VALU
// count). 8 independent load chains in flight per iteration.
__global__ __launch_bounds__(256) void gat_node_kernel(
    const int* __restrict__ rowptr, const int* __restrict__ csr,
    const float* __restrict__ asrc, const float* __restrict__ adst,
    const float* __restrict__ tab, const __half2* __restrict__ xs16,
    const float* __restrict__ b, float* __restrict__ out,
    short* __restrict__ oxh, short* __restrict__ oxl, int mode) {
  const int n = (blockIdx.x * blockDim.x + threadIdx.x) >> 6;
  if (n >= N_NODES) return;
  const int lane = threadIdx.x & 63;
  const int hh = lane >> 4;               // head of this lane's 4 cols
  const int cbase = lane << 2;
  const int i0 = rowptr[n], i1 = rowptr[n + 1];
  const float adn = adst[n * NHEAD + hh];
  const float treg = tab[lane * NHEAD + hh];   // lane = rel id (NREL==64)

  float4 acc = make_float4(0.f, 0.f, 0.f, 0.f);
  float den = 0.f;
  int i = i0;
  for (; i + 8 <= i1; i += 8) {
    int p[8];
#pragma unroll
    for (int k = 0; k < 8; ++k) p[k] = csr[i + k];
    float l[8];
    uint2 q[8];
#pragma unroll
    for (int k = 0; k < 8; ++k) {
      const int s = p[k] & 0xFFFF;
      l[k] = asrc[s * NHEAD + hh] + adn + __shfl(treg, p[k] >> 16);
      q[k] = *(const uint2*)&xs16[((size_t)s * HC + cbase) >> 1];
    }
#pragma unroll
    for (int k = 0; k < 8; ++k) {
      float lk = l[k];
      lk = (lk >= 0.f) ? lk : NEG_SLOPE * lk;
      const float w = __expf(lk);
      den += w;
      const float2 a = __half22float2(*(const __half2*)&q[k].x);
      const float2 c = __half22float2(*(const __half2*)&q[k].y);
      acc.x += w * a.x; acc.y += w * a.y; acc.z += w * c.x; acc.w += w * c.y;
    }
  }
  for (; i + 4 <= i1; i += 4) {
    const int p0 = csr[i], p1 = csr[i + 1], p2 = csr[i + 2], p3 = csr[i + 3];
    const int s0 = p0 & 0xFFFF, s1 = p1 & 0xFFFF, s2 = p2 & 0xFFFF, s3 = p3 & 0xFFFF;
    float l0 = asrc[s0 * NHEAD + hh] + adn + __shfl(treg, p0 >> 16);
    float l1 = asrc[s1 * NHEAD + hh] + adn + __shfl(treg, p1 >> 16);
    float l2 = asrc[s2 * NHEAD + hh] + adn + __shfl(treg, p2 >> 16);
    float l3 = asrc[s3 * NHEAD + hh] + adn + __shfl(treg, p3 >> 16);
    const uint2 q0 = *(const uint2*)&xs16[((size_t)s0 * HC + cbase) >> 1];
    const uint2 q1 = *(const uint2*)&xs16[((size_t)s1 * HC + cbase) >> 1];
    const uint2 q2 = *(const uint2*)&xs16[((size_t)s2 * HC + cbase) >> 1];
    const uint2 q3 = *(const uint2*)&xs16[((size_t)s3 * HC + cbase) >> 1];
    l0 = (l0 >= 0.f) ? l0 : NEG_SLOPE * l0;
    l1 = (l1 >= 0.f) ? l1 : NEG_SLOPE * l1;
    l2 = (l2 >= 0.f) ? l2 : NEG_SLOPE * l2;
    l3 = (l3 >= 0.f) ? l3 : NEG_SLOPE * l3;
    const float w0 = __expf(l0), w1 = __expf(l1), w2 = __expf(l2), w3 = __expf(l3);
    den += (w0 + w1) + (w2 + w3);
    const float2 a0 = __half22float2(*(const __half2*)&q0.x), b0 = __half22float2(*(const __half2*)&q0.y);
    const float2 a1 = __half22float2(*(const __half2*)&q1.x), b1 = __half22float2(*(const __half2*)&q1.y);
    const float2 a2 = __half22float2(*(const __half2*)&q2.x), b2 = __half22float2(*(const __half2*)&q2.y);
    const float2 a3 = __half22float2(*(const __half2*)&q3.x), b3 = __half22float2(*(const __half2*)&q3.y);
    acc.x += w0 * a0.x + w1 * a1.x + w2 * a2.x + w3 * a3.x;
    acc.y += w0 * a0.y + w1 * a1.y + w2 * a2.y + w3 * a3.y;
    acc.z += w0 * b0.x + w1 * b1.x + w2 * b2.x + w3 * b3.x;
    acc.w += w0 * b0.y + w1 * b1.y + w2 * b2.y + w3 * b3.y;
  }
  for (; i < i1; ++i) {
    const int p = csr[i];
    const int s = p & 0xFFFF;
    float l = asrc[s * NHEAD + hh] + adn + __shfl(treg, p >> 16);
    l = (l >= 0.f) ? l : NEG_SLOPE * l;
    const float w = __expf(l);
    const uint2 q = *(const uint2*)&xs16[((size_t)s * HC + cbase) >> 1];
    const float2 a = __half22float2(*(const __half2*)&q.x);
    const float2 c = __half22float2(*(const __half2*)&q.y);
    den += w;
    acc.x += w * a.x; acc.y += w * a.y; acc.z += w * c.x; acc.w += w * c.y;
  }

  const float rd = (den > 0.f) ? (0.25f / den) : 0.f;
  float4 y = make_float4(acc.x * rd, acc.y * rd, acc.z * rd, acc.w * rd);
#pragma unroll
  for (int off = 16; off < 64; off <<= 1) {
    y.x += __shfl_xor(y.x, off);
    y.y += __shfl_xor(y.y, off);
    y.z += __shfl_xor(y.z, off);
    y.w += __shfl_xor(y.w, off);
  }
  if (lane < 16) {
    const float4 bb = *(const float4*)&b[lane * 4];
    y.x += bb.x; y.y += bb.y; y.z += bb.z; y.w += bb.w;
    if (mode) {
      y.x = fmaxf(y.x, 0.f); y.y = fmaxf(y.y, 0.f);
      y.z = fmaxf(y.z, 0.f); y.w = fmaxf(y.w, 0.f);
      unsigned h0 = bf16rne(y.x), h1 = bf16rne(y.y);
      unsigned h2 = bf16rne(y.z), h3 = bf16rne(y.w);
      float l0 = (y.x - __uint_as_float(h0 << 16)) * 256.0f;
      float l1 = (y.y - __uint_as_float(h1 << 16)) * 256.0f;
      float l2 = (y.z - __uint_as_float(h2 << 16)) * 256.0f;
      float l3 = (y.w - __uint_as_float(h3 << 16)) * 256.0f;
      unsigned hp0 = h0 | (h1 << 16), hp1 = h2 | (h3 << 16);
      unsigned lp0 = bf16rne(l0) | (bf16rne(l1) << 16);
      unsigned lp1 = bf16rne(l2) | (bf16rne(l3) << 16);
      const int pk = lane >> 3;
      const int lip = (n & 15) + ((lane >> 1) & 3) * 16;
      const int j0 = (lane & 1) * 4;
      size_t base = ((size_t)((n >> 4) * 2 + pk) * 64 + lip) * 8 + j0;
      *(uint2*)&oxh[base] = make_uint2(hp0, hp1);
      *(uint2*)&oxl[base] = make_uint2(lp0, lp1);
    } else {
      *(float4*)&out[(size_t)n * 64 + lane * 4] = y;
    }
  }
}

extern "C" void kernel_launch(void* const* d_in, const int* in_sizes, int n_in,
                              void* d_out, int out_size, void* d_ws, size_t ws_size,
                              hipStream_t stream) {
  const float* x   = (const float*)d_in[0];
  const int* eidx  = (const int*)d_in[1];
  const int* etype = (const int*)d_in[2];
  const float* rel1 = (const float*)d_in[3];
  const float* W1   = (const float*)d_in[4];
  const float* We1  = (const float*)d_in[5];
  const float* as1  = (const float*)d_in[6];
  const float* ad1  = (const float*)d_in[7];
  const float* ae1  = (const float*)d_in[8];
  const float* b1   = (const float*)d_in[9];
  const float* rel2 = (const float*)d_in[10];
  const float* W2   = (const float*)d_in[11];
  const float* We2  = (const float*)d_in[12];
  const float* as2  = (const float*)d_in[13];
  const float* ad2  = (const float*)d_in[14];
  const float* ae2  = (const float*)d_in[15];
  const float* b2   = (const float*)d_in[16];
  const int* src = eidx;
  const int* dst = eidx + N_EDGES;

  // ---- workspace layout (256B-aligned regions) ----
  char* wsb = (char*)d_ws;
  size_t off = 0;
  auto carve = [&](size_t bytes) { char* p = wsb + off; off = (off + bytes + 255) & ~(size_t)255; return p; };
  __half2* xs16 = (__half2*)carve((size_t)N_NODES * HC * 2);          // 25.6MB
  float* asrc = (float*)carve((size_t)N_NODES * NHEAD * 4);
  float* adst = (float*)carve((size_t)N_NODES * NHEAD * 4);
  float* tab1 = (float*)carve(NREL * NHEAD * 4);
  float* tab2 = (float*)carve(NREL * NHEAD * 4);
  short* xfh  = (short*)carve(((size_t)N_NODES * IN_DIM + 32768) * 2);// 12.9MB
  short* xfl  = (short*)carve(((size_t)N_NODES * IN_DIM + 32768) * 2);
  short* w1h  = (short*)carve(256 * IN_DIM * 2);
  short* w1l  = (short*)carve(256 * IN_DIM * 2);
  short* w2h  = (short*)carve(256 * 64 * 2);
  short* w2l  = (short*)carve(256 * 64 * 2);
  int* deg    = (int*)carve(N_NODES * 4);
  int* rowptr = (int*)carve((N_NODES + 1) * 4);
  unsigned short* rank = (unsigned short*)carve((size_t)N_EDGES * 2);
  int* csrp   = (int*)carve((size_t)N_EDGES * 4);
  int* bsum   = (int*)carve(256 * 4);
  int* boff   = (int*)carve(256 * 4);

  hipMemsetAsync(deg, 0, N_NODES * sizeof(int), stream);

  // one atomic pass: counts + per-edge ranks
  hist_rank_kernel<<<HB, 256, 0, stream>>>(dst, deg, rank);

  // fused prep: prep_x(l1) | relalpha x2 | prep_w x2
  fused_prep<<<XB + 128 + 16 + 8, 256, 0, stream>>>(
      x, xfh, xfl,
      rel1, We1, ae1, rel2, We2, ae2, tab1, tab2,
      W1, w1h, w1l, W2, w2h, w2l);

  block_sum_kernel<<<SCAN_B, 256, 0, stream>>>(deg, bsum);
  scan_bsum_kernel<<<1, 256, 0, stream>>>(bsum, boff);
  scan_final_kernel<<<SCAN_B, 256, 0, stream>>>(deg, boff, rowptr);
  fill_kernel<<<HB, 256, 0, stream>>>(src, dst, etype, rank, rowptr, csrp);

  const dim3 gemm_grid((N_NODES + 63) / 64, 2);
  const int GB = (N_NODES * 64 + 255) / 256;   // one wave per node

  // ================= layer 1 =================
  gemm_mfma<<<gemm_grid, 256, 0, stream>>>(xfh, xfl, w1h, w1l, as1, ad1, xs16, asrc, adst, N_NODES, IN_DIM);
  gat_node_kernel<<<GB, 256, 0, stream>>>(rowptr, csrp, asrc, adst, tab1, xs16,
                                          b1, nullptr, xfh, xfl, 1);

  // ================= layer 2 =================
  gemm_mfma<<<gemm_grid, 256, 0, stream>>>(xfh, xfl, w2h, w2l, as2, ad2, xs16, asrc, adst, N_NODES, 64);
  gat_node_kernel<<<GB, 256, 0, stream>>>(rowptr, csrp, asrc, adst, tab2, xs16,
                                          b2, (float*)d_out, nullptr, nullptr, 0);
}